// Round 1
// baseline (1385.886 us; speedup 1.0000x reference)
//
#include <hip/hip_runtime.h>
#include <hip/hip_bf16.h>

// LightGCN forward on MI355X.
// R6: non-temporal edge streams. R5 counters showed fill_kernel at 262us with
//     322MB WRITE for 24MB of useful col[] data (13x write amplification):
//     the 192MB of streaming int4 edge reads evict partially-written dirty
//     col lines from the per-XCD L2 (col range = 3MB, fits 4MB L2) ->
//     premature writeback + write-allocate refetch. Fix: nt loads for edge
//     streams (fill+hist), nt for col read / zn store in pull (pure streams),
//     and scan_kernel now writes cursor[] directly (memcpy dispatch removed).

#define WAVE 64

typedef int nt_int4 __attribute__((ext_vector_type(4)));

// --- range helpers -------------------------------------------------------
__device__ __forceinline__ int hist_range(int d, int nu, int unu, int uni) {
    return (d < nu) ? (d / unu) : 4 + ((d - nu) / uni);
}

__global__ __launch_bounds__(256) void hist_kernel(const int* __restrict__ ue,
                                                   const int* __restrict__ ie,
                                                   int* __restrict__ deg,
                                                   int E, int nu, int unu, int uni,
                                                   int gpc, int NG) {
    int r = blockIdx.x & 7;
    int chunk = blockIdx.x >> 3;
    int g0 = chunk * gpc;
    int g1 = min(g0 + gpc, NG);
    for (int g = g0 + (int)threadIdx.x; g < g1; g += 256) {
        int e0 = g * 4;
        if (e0 + 3 < E) {
            nt_int4 u = __builtin_nontemporal_load((const nt_int4*)(ue + e0));
            nt_int4 v = __builtin_nontemporal_load((const nt_int4*)(ie + e0));
            int du[4] = {u.x, u.y, u.z, u.w};
            int di[4] = {nu + v.x, nu + v.y, nu + v.z, nu + v.w};
            #pragma unroll
            for (int t = 0; t < 4; ++t) {
                if (hist_range(du[t], nu, unu, uni) == r) atomicAdd(&deg[du[t]], 1);
                if (hist_range(di[t], nu, unu, uni) == r) atomicAdd(&deg[di[t]], 1);
            }
        } else {
            for (int e = e0; e < E; ++e) {
                int du = ue[e], di = nu + ie[e];
                if (hist_range(du, nu, unu, uni) == r) atomicAdd(&deg[du], 1);
                if (hist_range(di, nu, unu, uni) == r) atomicAdd(&deg[di], 1);
            }
        }
    }
}

__global__ void dinv_kernel(const int* __restrict__ deg, float* __restrict__ dinv,
                            float* __restrict__ drt, int N) {
    int n = blockIdx.x * blockDim.x + threadIdx.x;
    if (n < N) {
        int d = deg[n];
        dinv[n] = (d > 0) ? rsqrtf((float)d) : 0.0f;
        drt[n]  = (d > 0) ? sqrtf((float)d)  : 0.0f;
    }
}

__global__ __launch_bounds__(1024) void scan_kernel(const int* __restrict__ deg,
                                                    int* __restrict__ offs,
                                                    int* __restrict__ cursor, int n) {
    __shared__ int wsum[16];
    const int T = 1024;
    const int per = 148;  // multiple of 4; 1024*148 >= 150000
    int t = threadIdx.x;
    int s0 = min(t * per, n);
    int s1 = min(s0 + per, n);

    int local = 0;
    int i = s0;
    for (; i + 3 < s1; i += 4) {
        int4 d = *(const int4*)(deg + i);
        local += d.x + d.y + d.z + d.w;
    }
    for (; i < s1; ++i) local += deg[i];

    int lane = t & 63, w = t >> 6;
    int v = local;
    #pragma unroll
    for (int d = 1; d < 64; d <<= 1) {
        int o = __shfl_up(v, d, 64);
        if (lane >= d) v += o;
    }
    if (lane == 63) wsum[w] = v;
    __syncthreads();
    if (t == 0) {
        int r = 0;
        #pragma unroll
        for (int k = 0; k < 16; ++k) { int s = wsum[k]; wsum[k] = r; r += s; }
    }
    __syncthreads();
    int excl = (v - local) + wsum[w];

    int run = excl;
    i = s0;
    for (; i + 3 < s1; i += 4) {
        int4 d = *(const int4*)(deg + i);
        int4 o;
        o.x = run; run += d.x;
        o.y = run; run += d.y;
        o.z = run; run += d.z;
        o.w = run; run += d.w;
        *(int4*)(offs + i) = o;
        *(int4*)(cursor + i) = o;
    }
    for (; i < s1; ++i) { offs[i] = run; cursor[i] = run; run += deg[i]; }
    if (t == T - 1) offs[n] = run;  // grand total = 2E
}

__global__ void bounds_kernel(const int* __restrict__ offs, int* __restrict__ bounds,
                              int N, int S) {
    int n = blockIdx.x * blockDim.x + threadIdx.x;
    if (n >= 1 && n < N) {
        int lo = offs[n - 1], hi = offs[n];
        #pragma unroll
        for (int k = 1; k < 8; ++k) {
            int t = k * S;
            if (lo < t && hi >= t) bounds[k] = n;
        }
    }
}

__global__ __launch_bounds__(256) void fill_kernel(const int* __restrict__ ue,
                                                   const int* __restrict__ ie,
                                                   const int* __restrict__ bounds,
                                                   int* __restrict__ cursor,
                                                   int* __restrict__ col,
                                                   int E, int nu, int gpc, int NG) {
    int r = blockIdx.x & 7;
    int chunk = blockIdx.x >> 3;
    int b1 = bounds[1], b2 = bounds[2], b3 = bounds[3], b4 = bounds[4];
    int b5 = bounds[5], b6 = bounds[6], b7 = bounds[7];
    int g0 = chunk * gpc;
    int g1 = min(g0 + gpc, NG);
    for (int g = g0 + (int)threadIdx.x; g < g1; g += 256) {
        int e0 = g * 4;
        if (e0 + 3 < E) {
            nt_int4 u = __builtin_nontemporal_load((const nt_int4*)(ue + e0));
            nt_int4 v = __builtin_nontemporal_load((const nt_int4*)(ie + e0));
            int du[4] = {u.x, u.y, u.z, u.w};
            int di[4] = {nu + v.x, nu + v.y, nu + v.z, nu + v.w};
            #pragma unroll
            for (int t = 0; t < 4; ++t) {
                int d = di[t];
                int rr = (d >= b1) + (d >= b2) + (d >= b3) + (d >= b4)
                       + (d >= b5) + (d >= b6) + (d >= b7);
                if (rr == r) { int p = atomicAdd(&cursor[d], 1); col[p] = du[t]; }
                d = du[t];
                rr = (d >= b1) + (d >= b2) + (d >= b3) + (d >= b4)
                   + (d >= b5) + (d >= b6) + (d >= b7);
                if (rr == r) { int p = atomicAdd(&cursor[d], 1); col[p] = di[t]; }
            }
        } else {
            for (int e = e0; e < E; ++e) {
                int du = ue[e], di = nu + ie[e];
                int d = di;
                int rr = (d >= b1) + (d >= b2) + (d >= b3) + (d >= b4)
                       + (d >= b5) + (d >= b6) + (d >= b7);
                if (rr == r) { int p = atomicAdd(&cursor[d], 1); col[p] = du; }
                d = du;
                rr = (d >= b1) + (d >= b2) + (d >= b3) + (d >= b4)
                   + (d >= b5) + (d >= b6) + (d >= b7);
                if (rr == r) { int p = atomicAdd(&cursor[d], 1); col[p] = di; }
            }
        }
    }
}

__global__ void init_z_kernel(const float* __restrict__ Gu, const float* __restrict__ Gi,
                              const float* __restrict__ dinv,
                              float* __restrict__ z, int nuQ, int totQ) {
    int i = blockIdx.x * blockDim.x + threadIdx.x;  // float4 slots
    if (i < totQ) {
        const float4* src = (i < nuQ) ? (const float4*)Gu : (const float4*)Gi;
        int j = (i < nuQ) ? i : i - nuQ;
        float4 a = src[j];
        float w = dinv[i >> 4];
        a.x *= w; a.y *= w; a.z *= w; a.w *= w;
        ((float4*)z)[i] = a;
    }
}

__global__ void init_bacc_kernel(const float* __restrict__ Gu, const float* __restrict__ Gi,
                                 const int* __restrict__ users, const int* __restrict__ items,
                                 float* __restrict__ baccU, float* __restrict__ baccI, int B) {
    int id = blockIdx.x * blockDim.x + threadIdx.x;  // B*16 float4 slots
    if (id < B * 16) {
        int b = id >> 4, q = id & 15;
        ((float4*)baccU)[id] = ((const float4*)Gu)[(size_t)users[b] * 16 + q];
        ((float4*)baccI)[id] = ((const float4*)Gi)[(size_t)items[b] * 16 + q];
    }
}

__global__ void mark_kernel(const int* __restrict__ users, const int* __restrict__ items,
                            int* __restrict__ flag, int B, int nu) {
    int b = blockIdx.x * blockDim.x + threadIdx.x;
    if (b < B) {
        flag[users[b]] = 1;
        flag[nu + items[b]] = 1;
    }
}

__global__ void compact_kernel(const int* __restrict__ flag, int* __restrict__ list,
                               int* __restrict__ cnt, int N) {
    int n = blockIdx.x * blockDim.x + threadIdx.x;
    if (n < N && flag[n]) {
        int pos = atomicAdd(cnt, 1);
        list[pos] = n;
    }
}

// One wave per destination row. z_next[r] = dinv[r]^2 * sum_{c in N(r)} z[c].
__global__ __launch_bounds__(256) void pull_kernel(const float* __restrict__ z,
                                                   float* __restrict__ zn,
                                                   const int* __restrict__ offs,
                                                   const int* __restrict__ col,
                                                   const float* __restrict__ dinv,
                                                   const int* __restrict__ rows,
                                                   const int* __restrict__ n_ptr, int N) {
    int wid = (blockIdx.x * blockDim.x + threadIdx.x) >> 6;
    int lane = threadIdx.x & 63;
    int nrows = rows ? *n_ptr : N;
    if (wid >= nrows) return;
    int r = rows ? rows[wid] : wid;
    int s = offs[r], e = offs[r + 1];
    float acc0 = 0.0f, acc1 = 0.0f;
    for (int base = s; base < e; base += 64) {
        int idx = base + lane;
        int c = (idx < e) ? __builtin_nontemporal_load(col + idx) : 0;
        int n = min(64, e - base);
        int j = 0;
        for (; j + 4 <= n; j += 4) {
            int c0 = __shfl(c, j),     c1 = __shfl(c, j + 1);
            int c2 = __shfl(c, j + 2), c3 = __shfl(c, j + 3);
            float v0 = z[(size_t)c0 * WAVE + lane];
            float v1 = z[(size_t)c1 * WAVE + lane];
            float v2 = z[(size_t)c2 * WAVE + lane];
            float v3 = z[(size_t)c3 * WAVE + lane];
            acc0 += v0 + v1;
            acc1 += v2 + v3;
        }
        for (; j < n; ++j) {
            int cj = __shfl(c, j);
            acc0 += z[(size_t)cj * WAVE + lane];
        }
    }
    float w = dinv[r];
    __builtin_nontemporal_store(w * w * (acc0 + acc1), zn + (size_t)r * WAVE + lane);
}

__global__ void gather_acc_kernel(const float* __restrict__ zn,
                                  const float* __restrict__ drt,
                                  const int* __restrict__ users, const int* __restrict__ items,
                                  float* __restrict__ baccU, float* __restrict__ baccI,
                                  int B, int nu) {
    int id = blockIdx.x * blockDim.x + threadIdx.x;  // B*16 float4 slots
    if (id < B * 16) {
        int b = id >> 4, q = id & 15;
        int u = users[b], it = nu + items[b];
        float wu = drt[u], wi = drt[it];
        float4 a = ((float4*)baccU)[id];
        float4 v = ((const float4*)zn)[(size_t)u * 16 + q];
        a.x += wu * v.x; a.y += wu * v.y; a.z += wu * v.z; a.w += wu * v.w;
        ((float4*)baccU)[id] = a;
        float4 c = ((float4*)baccI)[id];
        float4 d = ((const float4*)zn)[(size_t)it * 16 + q];
        c.x += wi * d.x; c.y += wi * d.y; c.z += wi * d.z; c.w += wi * d.w;
        ((float4*)baccI)[id] = c;
    }
}

// LDS-tiled fp32 GEMM + fused epilogue.
// Block: 64 batch-rows x 64 outputs, 256 threads, 4x4 reg tile/thread.
// K loop: 32 tiles of 32 feats; double-buffered LDS, 1 barrier/tile.
// Ft[buf][kk][row], Wt[buf][kk][col] — b128 fragment reads (broadcast/2-way).
__global__ __launch_bounds__(256) void proj_out_kernel(const float* __restrict__ baccU,
                                                       const float* __restrict__ baccI,
                                                       const float* __restrict__ Tu,
                                                       const float* __restrict__ F,
                                                       const float* __restrict__ W,
                                                       const float* __restrict__ bvec,
                                                       const int* __restrict__ users,
                                                       const int* __restrict__ items,
                                                       float* __restrict__ out,
                                                       int B, float invL) {
    const int FEATn = 1024;
    __shared__ float Ft[2][32][64];
    __shared__ float Wt[2][32][64];

    int tid = threadIdx.x;
    int tx = tid & 15;        // col group (4 cols)
    int ty = tid >> 4;        // row group (4 rows)
    int r0 = blockIdx.x * 64;

    // staging assignment: thread loads 2 float4 of one F row + one W row
    int lr = tid >> 2;                       // 0..63
    int lq = tid & 3;                        // quad group: local kk 4*lq and 4*lq+16
    int frow = min(r0 + lr, B - 1);
    const float* Fp = F + (size_t)items[frow] * FEATn + lq * 4;
    const float* Wp = W + (size_t)lr * FEATn + lq * 4;

    float4 fa0 = *(const float4*)(Fp);
    float4 fa1 = *(const float4*)(Fp + 16);
    float4 wa0 = *(const float4*)(Wp);
    float4 wa1 = *(const float4*)(Wp + 16);

    float acc[4][4] = {};

    for (int kt = 0; kt < 32; ++kt) {
        int buf = kt & 1;
        #pragma unroll
        for (int i = 0; i < 4; ++i) {
            Ft[buf][lq * 4 + i][lr]      = ((const float*)&fa0)[i];
            Ft[buf][lq * 4 + 16 + i][lr] = ((const float*)&fa1)[i];
            Wt[buf][lq * 4 + i][lr]      = ((const float*)&wa0)[i];
            Wt[buf][lq * 4 + 16 + i][lr] = ((const float*)&wa1)[i];
        }
        __syncthreads();
        if (kt < 31) {
            const float* fp = Fp + (kt + 1) * 32;
            const float* wp = Wp + (kt + 1) * 32;
            fa0 = *(const float4*)(fp);
            fa1 = *(const float4*)(fp + 16);
            wa0 = *(const float4*)(wp);
            wa1 = *(const float4*)(wp + 16);
        }
        #pragma unroll 8
        for (int kk = 0; kk < 32; ++kk) {
            float4 a = *(const float4*)&Ft[buf][kk][ty * 4];
            float4 b = *(const float4*)&Wt[buf][kk][tx * 4];
            acc[0][0] = fmaf(a.x, b.x, acc[0][0]);
            acc[0][1] = fmaf(a.x, b.y, acc[0][1]);
            acc[0][2] = fmaf(a.x, b.z, acc[0][2]);
            acc[0][3] = fmaf(a.x, b.w, acc[0][3]);
            acc[1][0] = fmaf(a.y, b.x, acc[1][0]);
            acc[1][1] = fmaf(a.y, b.y, acc[1][1]);
            acc[1][2] = fmaf(a.y, b.z, acc[1][2]);
            acc[1][3] = fmaf(a.y, b.w, acc[1][3]);
            acc[2][0] = fmaf(a.z, b.x, acc[2][0]);
            acc[2][1] = fmaf(a.z, b.y, acc[2][1]);
            acc[2][2] = fmaf(a.z, b.z, acc[2][2]);
            acc[2][3] = fmaf(a.z, b.w, acc[2][3]);
            acc[3][0] = fmaf(a.w, b.x, acc[3][0]);
            acc[3][1] = fmaf(a.w, b.y, acc[3][1]);
            acc[3][2] = fmaf(a.w, b.z, acc[3][2]);
            acc[3][3] = fmaf(a.w, b.w, acc[3][3]);
        }
    }

    // fused epilogue: bias, row-normalize (16-lane groups hold a full row), dots
    float4 bb = *(const float4*)(bvec + tx * 4);
    float L2 = invL * invL;
    float res[4];
    #pragma unroll
    for (int r = 0; r < 4; ++r) {
        int gr = min(r0 + ty * 4 + r, B - 1);
        float pb0 = acc[r][0] + bb.x;
        float pb1 = acc[r][1] + bb.y;
        float pb2 = acc[r][2] + bb.z;
        float pb3 = acc[r][3] + bb.w;
        float s = pb0 * pb0 + pb1 * pb1 + pb2 * pb2 + pb3 * pb3;
        #pragma unroll
        for (int d = 1; d < 16; d <<= 1) s += __shfl_xor(s, d, 64);
        float inv = 1.0f / fmaxf(sqrtf(s), 1e-12f);
        int u = users[gr];
        float4 tu = *(const float4*)(Tu + (size_t)u * WAVE + tx * 4);
        float4 gu = *(const float4*)(baccU + (size_t)gr * WAVE + tx * 4);
        float4 gi = *(const float4*)(baccI + (size_t)gr * WAVE + tx * 4);
        float dsum = L2 * (gu.x * gi.x + gu.y * gi.y + gu.z * gi.z + gu.w * gi.w)
                   + inv * (tu.x * pb0 + tu.y * pb1 + tu.z * pb2 + tu.w * pb3);
        #pragma unroll
        for (int d = 1; d < 16; d <<= 1) dsum += __shfl_xor(dsum, d, 64);
        res[r] = dsum;
    }
    if (tx == 0) {
        #pragma unroll
        for (int r = 0; r < 4; ++r) {
            int gr = r0 + ty * 4 + r;
            if (gr < B) out[gr] = res[r];
        }
    }
}

extern "C" void kernel_launch(void* const* d_in, const int* in_sizes, int n_in,
                              void* d_out, int out_size, void* d_ws, size_t ws_size,
                              hipStream_t stream) {
    const float* Gu = (const float*)d_in[0];
    const float* Gi = (const float*)d_in[1];
    const float* Tu = (const float*)d_in[2];
    const float* F  = (const float*)d_in[3];
    const float* W  = (const float*)d_in[4];
    const float* bv = (const float*)d_in[5];
    const int* ue    = (const int*)d_in[6];
    const int* ie    = (const int*)d_in[7];
    const int* users = (const int*)d_in[8];
    const int* items = (const int*)d_in[9];
    float* out = (float*)d_out;

    const int K  = 64;
    const int nu = in_sizes[0] / K;
    const int ni = in_sizes[1] / K;
    const int N  = nu + ni;
    const int E  = in_sizes[6];
    const int B  = in_sizes[8];

    char* p = (char*)d_ws;
    auto alloc = [&](size_t bytes) -> void* {
        void* r = (void*)p;
        p += (bytes + 255) & ~(size_t)255;
        return r;
    };
    int*   deg    = (int*)  alloc((size_t)N * 4);
    float* dinv   = (float*)alloc((size_t)N * 4);
    float* drt    = (float*)alloc((size_t)N * 4);
    int*   offs   = (int*)  alloc((size_t)(N + 1) * 4);
    int*   cursor = (int*)  alloc((size_t)N * 4);   // reused as flag[] after fill
    int*   col    = (int*)  alloc((size_t)2 * E * 4);
    float* za     = (float*)alloc((size_t)N * K * 4);
    float* zb     = (float*)alloc((size_t)N * K * 4);
    float* baccU  = (float*)alloc((size_t)B * K * 4);
    float* baccI  = (float*)alloc((size_t)B * K * 4);
    int*   list   = (int*)  alloc((size_t)2 * B * 4);
    int*   cnt    = (int*)  alloc(256);
    int*   bounds = (int*)  alloc(256);

    const int NG  = (E + 3) / 4;          // int4 edge groups
    const int CH  = 1024;                 // edge chunks per range
    const int gpc = (NG + CH - 1) / CH;   // groups per chunk
    const int grid8 = 8 * CH;
    const int unu = (nu + 3) / 4, uni = (ni + 3) / 4;

    // graph build
    hipMemsetAsync(deg, 0, (size_t)N * 4, stream);
    hist_kernel<<<grid8, 256, 0, stream>>>(ue, ie, deg, E, nu, unu, uni, gpc, NG);
    dinv_kernel<<<(N + 255) / 256, 256, 0, stream>>>(deg, dinv, drt, N);
    scan_kernel<<<1, 1024, 0, stream>>>(deg, offs, cursor, N);
    bounds_kernel<<<(N + 255) / 256, 256, 0, stream>>>(offs, bounds, N, (2 * E) / 8);
    fill_kernel<<<grid8, 256, 0, stream>>>(ue, ie, bounds, cursor, col, E, nu, gpc, NG);

    // batch-node list (cursor reused as flags)
    hipMemsetAsync(cursor, 0, (size_t)N * 4, stream);
    hipMemsetAsync(cnt, 0, 4, stream);
    mark_kernel<<<(B + 255) / 256, 256, 0, stream>>>(users, items, cursor, B, nu);
    compact_kernel<<<(N + 255) / 256, 256, 0, stream>>>(cursor, list, cnt, N);

    // init
    int totQ = N * K / 4, nuQ = nu * K / 4;
    init_z_kernel<<<(totQ + 255) / 256, 256, 0, stream>>>(Gu, Gi, dinv, za, nuQ, totQ);
    init_bacc_kernel<<<(B * 16 + 255) / 256, 256, 0, stream>>>(Gu, Gi, users, items,
                                                               baccU, baccI, B);

    // layer 1 (full)
    pull_kernel<<<(N + 3) / 4, 256, 0, stream>>>(za, zb, offs, col, dinv,
                                                 nullptr, nullptr, N);
    gather_acc_kernel<<<(B * 16 + 255) / 256, 256, 0, stream>>>(zb, drt, users, items,
                                                                baccU, baccI, B, nu);
    // layer 2 (full)
    pull_kernel<<<(N + 3) / 4, 256, 0, stream>>>(zb, za, offs, col, dinv,
                                                 nullptr, nullptr, N);
    gather_acc_kernel<<<(B * 16 + 255) / 256, 256, 0, stream>>>(za, drt, users, items,
                                                                baccU, baccI, B, nu);
    // layer 3 (sparse: only unique batch rows)
    pull_kernel<<<(2 * B + 3) / 4, 256, 0, stream>>>(za, zb, offs, col, dinv,
                                                     list, cnt, N);
    gather_acc_kernel<<<(B * 16 + 255) / 256, 256, 0, stream>>>(zb, drt, users, items,
                                                                baccU, baccI, B, nu);

    // epilogue: LDS-tiled GEMM + fused norm/dots
    proj_out_kernel<<<(B + 63) / 64, 256, 0, stream>>>(baccU, baccI, Tu, F, W, bv,
                                                       users, items, out, B, 0.25f);
}